// Round 4
// baseline (2466.910 us; speedup 1.0000x reference)
//
#include <hip/hip_runtime.h>

#define T_STEPS 512
#define BATCH   256
#define N_INP   128
#define N_HID   512
#define N_OUT   10

#define DT_C     0.042f
#define GAMMA_C  2.7f
#define EPS_C    4.7f

#define NWG        64      // 8 m-groups (32 rows) x 8 n-tiles (64 cols)
#define GROUP_WGS  8       // WGs per row-group (share one flag set)
#define WG_THREADS 512     // 8 waves, 8-way K-split

typedef short          s16x8  __attribute__((ext_vector_type(8)));
typedef float          f32x16 __attribute__((ext_vector_type(16)));
typedef float          f32x4  __attribute__((ext_vector_type(4)));
typedef unsigned short u16x4  __attribute__((ext_vector_type(4)));
typedef unsigned long long u64;

__device__ inline unsigned short f2bf(float f) {
  union { float f; unsigned u; } v; v.f = f;
  unsigned r = v.u + 0x7fffu + ((v.u >> 16) & 1u);   // RNE
  return (unsigned short)(r >> 16);
}
__device__ inline float bf2f(unsigned short h) {
  union { unsigned u; float f; } v; v.u = ((unsigned)h) << 16;
  return v.f;
}

// agent-scope relaxed store: write-through to the coherence point (IC). Proven R4-R6 + R0.
__device__ inline void pub8(unsigned short* p, u16x4 v) {
  union { u16x4 v; u64 q; } u; u.v = v;
  __hip_atomic_store((u64*)p, u.q, __ATOMIC_RELAXED, __HIP_MEMORY_SCOPE_AGENT);
}

// 8 coherent 16B loads + waitcnt fused in ONE asm block (R6 lesson: the backend
// doesn't model asm loads, so the waitcnt must live in the same asm block every
// consumer data-depends on). Outputs earlyclobber vs the address pair.
#define STATE_LD8(HB, HP)                                                    \
  asm volatile(                                                              \
    "global_load_dwordx4 %0, %8, off sc0 sc1\n\t"                            \
    "global_load_dwordx4 %1, %8, off offset:32 sc0 sc1\n\t"                  \
    "global_load_dwordx4 %2, %8, off offset:64 sc0 sc1\n\t"                  \
    "global_load_dwordx4 %3, %8, off offset:96 sc0 sc1\n\t"                  \
    "global_load_dwordx4 %4, %8, off offset:128 sc0 sc1\n\t"                 \
    "global_load_dwordx4 %5, %8, off offset:160 sc0 sc1\n\t"                 \
    "global_load_dwordx4 %6, %8, off offset:192 sc0 sc1\n\t"                 \
    "global_load_dwordx4 %7, %8, off offset:224 sc0 sc1\n\t"                 \
    "s_waitcnt vmcnt(0)"                                                     \
    : "=&v"(HB[0]), "=&v"(HB[1]), "=&v"(HB[2]), "=&v"(HB[3]),                \
      "=&v"(HB[4]), "=&v"(HB[5]), "=&v"(HB[6]), "=&v"(HB[7])                 \
    : "v"(HP)                                                                \
    : "memory")

// Persistent recurrent kernel (plain launch; 64 blocks of 8 waves => 1 WG/CU,
// trivially co-resident). EXACT R0-proven protocol (agent/IC scope throughout);
// only delta vs R0 is the x one-step software prefetch (plain loads, issued
// right after STATE_LD8 so the HBM/L2 latency hides under the state MFMAs +
// reduce instead of stalling the x-MFMA at loop top).
// Hbf: double-buffered published state, bf16 [2][256][1024]; col c<512 = hz[c]
//      (W row 128+c), col 512+c = hy[c] (W row 640+c).
__global__ __launch_bounds__(WG_THREADS, 2) void cornn_kernel(
    const float* __restrict__ x, const float* __restrict__ W,
    const float* __restrict__ bias, unsigned short* __restrict__ Hbf,
    float* __restrict__ Hy32, unsigned* __restrict__ flags_ws) {
  const int tid   = threadIdx.x;
  const int lane  = tid & 63;
  const int ks    = tid >> 6;        // wave id 0..7 (8-way K-split)
  const int half  = lane >> 5;       // A/B frag k-half
  const int half8 = half << 3;
  const int lcol  = lane & 31;
  const int mi    = blockIdx.x & 7;  // row group
  const int ni    = blockIdx.x >> 3; // 64-col tile, 0..7
  const int rowA  = (mi << 5) + lcol;

  unsigned* gflags = flags_ws + mi * 64;   // 8 dwords used per group, 256B stride

  __shared__ float sC[8][2048];   // K-split partials (32 rows x 64 cols), 64 KB
  __shared__ float sB[64];

  // ---- stage W in registers: state 8 chunks/wave x 2 col-tiles (hi+lo),
  //      x 1 chunk/wave x 2 col-tiles (hi+lo) ----
  s16x8 whi0[8], wlo0[8], whi1[8], wlo1[8];
  s16x8 wxhi0, wxlo0, wxhi1, wxlo1;
  const int c0t = (ni << 6) + lcol;      // col tile 0
  #pragma unroll
  for (int i = 0; i < 8; ++i) {
    const int wr = 128 + (ks << 7) + i * 16 + half8;
    const float* wp0 = W + (size_t)wr * N_HID + c0t;
    s16x8 hi0, lo0, hi1, lo1;
    #pragma unroll
    for (int j = 0; j < 8; ++j) {
      float f0 = wp0[(size_t)j * N_HID];
      float f1 = wp0[(size_t)j * N_HID + 32];
      unsigned short h0 = f2bf(f0), h1 = f2bf(f1);
      hi0[j] = (short)h0;  lo0[j] = (short)f2bf(f0 - bf2f(h0));
      hi1[j] = (short)h1;  lo1[j] = (short)f2bf(f1 - bf2f(h1));
    }
    whi0[i] = hi0; wlo0[i] = lo0; whi1[i] = hi1; wlo1[i] = lo1;
  }
  {
    const int wr = (ks << 4) + half8;    // x chunk ks: k = ks*16
    const float* wp0 = W + (size_t)wr * N_HID + c0t;
    s16x8 hi0, lo0, hi1, lo1;
    #pragma unroll
    for (int j = 0; j < 8; ++j) {
      float f0 = wp0[(size_t)j * N_HID];
      float f1 = wp0[(size_t)j * N_HID + 32];
      unsigned short h0 = f2bf(f0), h1 = f2bf(f1);
      hi0[j] = (short)h0;  lo0[j] = (short)f2bf(f0 - bf2f(h0));
      hi1[j] = (short)h1;  lo1[j] = (short)f2bf(f1 - bf2f(h1));
    }
    wxhi0 = hi0; wxlo0 = lo0; wxhi1 = hi1; wxlo1 = lo1;
  }
  if (tid < 64) sB[tid] = bias[(ni << 6) + tid];

  // ---- per-thread fp32 state (4 cols each; 512 thr x 4 = 32 rows x 64 cols) ----
  const int e0   = tid << 2;
  const int rowL = e0 >> 6, c0 = e0 & 63;
  const int rowG = (mi << 5) + rowL;
  const int colG = (ni << 6) + c0;
  f32x4 hz = {0.f, 0.f, 0.f, 0.f};
  f32x4 hy = {0.f, 0.f, 0.f, 0.f};

  // state-read base pointers (per lane), one per buffer
  const unsigned short* hb2[2];
  hb2[0] = Hbf + (size_t)rowA * 1024 + (ks << 7) + half8;
  hb2[1] = hb2[0] + 256 * 1024;
  // publish pointers (per thread), one per buffer
  unsigned short* wz[2];
  unsigned short* wy[2];
  wz[0] = Hbf + (size_t)rowG * 1024 + colG;       wz[1] = wz[0] + 256 * 1024;
  wy[0] = wz[0] + 512;                            wy[1] = wz[1] + 512;

  __syncthreads();   // sB visible

  // ---- x software pipeline: x(t) in registers at loop top; x(t+1) issued
  // right after STATE_LD8's vmcnt(0). Plain loads: the compiler tracks them
  // and inserts the waitcnt before use (the slow protocol's __syncthreads
  // drains vmcnt anyway), so this is protocol-identical to R0.
  const float* xbase = x + (size_t)rowA * N_INP + (ks << 4) + half8;
  f32x4 xr0 = *reinterpret_cast<const f32x4*>(xbase);
  f32x4 xr1 = *reinterpret_cast<const f32x4*>(xbase + 4);

  for (int t = 0; t < T_STEPS; ++t) {
    f32x16 acc0 = {};
    f32x16 acc1 = {};

    // ---- x-part (no state dep): every wave does its 16-k chunk ----
    {
      s16x8 ahi, alo;
      #pragma unroll
      for (int j = 0; j < 4; ++j) {
        float f0 = xr0[j], f1 = xr1[j];
        unsigned short h0 = f2bf(f0), h1 = f2bf(f1);
        ahi[j]     = (short)h0;  ahi[j + 4] = (short)h1;
        alo[j]     = (short)f2bf(f0 - bf2f(h0));
        alo[j + 4] = (short)f2bf(f1 - bf2f(h1));
      }
      acc0 = __builtin_amdgcn_mfma_f32_32x32x16_bf16(ahi, wxhi0, acc0, 0, 0, 0);
      acc0 = __builtin_amdgcn_mfma_f32_32x32x16_bf16(ahi, wxlo0, acc0, 0, 0, 0);
      acc0 = __builtin_amdgcn_mfma_f32_32x32x16_bf16(alo, wxhi0, acc0, 0, 0, 0);
      acc1 = __builtin_amdgcn_mfma_f32_32x32x16_bf16(ahi, wxhi1, acc1, 0, 0, 0);
      acc1 = __builtin_amdgcn_mfma_f32_32x32x16_bf16(ahi, wxlo1, acc1, 0, 0, 0);
      acc1 = __builtin_amdgcn_mfma_f32_32x32x16_bf16(alo, wxhi1, acc1, 0, 0, 0);
    }

    f32x4 xn0, xn1;
    const float* xpn =
        xbase + (size_t)((t + 1 < T_STEPS) ? t + 1 : t) * (BATCH * N_INP);

    if (t > 0) {
      // ---- per-wave poll of the 8 group flags (skip own; no join barrier) ----
      const unsigned ep = (unsigned)t;
      const int l = lane & 7;
      for (;;) {
        unsigned v = __hip_atomic_load(&gflags[l], __ATOMIC_RELAXED, __HIP_MEMORY_SCOPE_AGENT);
        if (__ballot((lane >= 8) | (l == ni) | (v >= ep)) == ~0ull) break;
        __builtin_amdgcn_s_sleep(2);
      }

      // ---- state part: 8 pipelined coherent 16B loads, ONE round-trip ----
      const unsigned short* hp = hb2[t & 1];
      f32x4 hbuf[8];
      STATE_LD8(hbuf, hp);

      // issue x(t+1) now: hides under the state MFMAs + reduce
      xn0 = *reinterpret_cast<const f32x4*>(xpn);
      xn1 = *reinterpret_cast<const f32x4*>(xpn + 4);

      #pragma unroll
      for (int i = 0; i < 8; ++i) {
        union { f32x4 f; s16x8 s; } u; u.f = hbuf[i];
        acc0 = __builtin_amdgcn_mfma_f32_32x32x16_bf16(u.s, whi0[i], acc0, 0, 0, 0);
        acc0 = __builtin_amdgcn_mfma_f32_32x32x16_bf16(u.s, wlo0[i], acc0, 0, 0, 0);
        acc1 = __builtin_amdgcn_mfma_f32_32x32x16_bf16(u.s, whi1[i], acc1, 0, 0, 0);
        acc1 = __builtin_amdgcn_mfma_f32_32x32x16_bf16(u.s, wlo1[i], acc1, 0, 0, 0);
      }
    } else {
      xn0 = *reinterpret_cast<const f32x4*>(xpn);
      xn1 = *reinterpret_cast<const f32x4*>(xpn + 4);
    }

    // ---- K-split partials (C/D layout: col=lane&31, row=(r&3)+8*(r>>2)+4*half) ----
    #pragma unroll
    for (int r = 0; r < 16; ++r) {
      const int rowL_r = (r & 3) + ((r >> 2) << 3) + (half << 2);
      sC[ks][rowL_r * 64 + lcol]      = acc0[r];
      sC[ks][rowL_r * 64 + 32 + lcol] = acc1[r];
    }
    __syncthreads();

    // ---- reduce (8-way) + tanh + state update + publish ----
    {
      f32x4 s = *reinterpret_cast<f32x4*>(&sC[0][e0]);
      #pragma unroll
      for (int w = 1; w < 8; ++w) s += *reinterpret_cast<f32x4*>(&sC[w][e0]);
      u16x4 pz, py;
      #pragma unroll
      for (int j = 0; j < 4; ++j) {
        float pre = tanhf(s[j] + sB[c0 + j]);
        float z = hz[j] + DT_C * (pre - GAMMA_C * hy[j] - EPS_C * hz[j]);
        float y = hy[j] + DT_C * z;
        hz[j] = z; hy[j] = y;
        pz[j] = f2bf(z); py[j] = f2bf(y);
      }
      const int wb = (t & 1) ^ 1;
      pub8(wz[wb], pz);
      pub8(wy[wb], py);
    }
    __syncthreads();   // drains vmcnt: publishes acked at coherence point before flag
    if (tid == 0)
      __hip_atomic_store(&gflags[ni], (unsigned)t + 1u, __ATOMIC_RELAXED, __HIP_MEMORY_SCOPE_AGENT);
    xr0 = xn0; xr1 = xn1;
  }

  if (Hy32 != nullptr)
    *reinterpret_cast<f32x4*>(Hy32 + (size_t)rowG * 512 + colG) = hy;
}

// out[b][c] = sum_k hy[b][k] * Wout[k][c] + bout[c]
__global__ void cornn_out_kernel(const float* __restrict__ Hy32,
                                 const unsigned short* __restrict__ HbfFinal,
                                 const float* __restrict__ Wout,
                                 const float* __restrict__ bout,
                                 float* __restrict__ out) {
  const int b = blockIdx.x;
  const int lane = threadIdx.x;   // 64 threads
  float a[N_OUT];
  #pragma unroll
  for (int c = 0; c < N_OUT; ++c) a[c] = 0.f;
  #pragma unroll
  for (int j = 0; j < 8; ++j) {
    const int k = lane + (j << 6);
    const float h = Hy32 ? Hy32[(size_t)b * N_HID + k]
                         : bf2f(HbfFinal[(size_t)b * 1024 + 512 + k]);
    const float* wr = Wout + (size_t)k * N_OUT;
    #pragma unroll
    for (int c = 0; c < N_OUT; ++c) a[c] += h * wr[c];
  }
  #pragma unroll
  for (int c = 0; c < N_OUT; ++c) {
    float v = a[c];
    for (int off = 32; off > 0; off >>= 1) v += __shfl_down(v, off, 64);
    if (lane == 0) out[(size_t)b * N_OUT + c] = v + bout[c];
  }
}

extern "C" void kernel_launch(void* const* d_in, const int* in_sizes, int n_in,
                              void* d_out, int out_size, void* d_ws, size_t ws_size,
                              hipStream_t stream) {
  (void)in_sizes; (void)n_in; (void)out_size;
  const float* x    = (const float*)d_in[0];
  const float* W    = (const float*)d_in[1];
  const float* bias = (const float*)d_in[2];
  const float* Wout = (const float*)d_in[3];
  const float* bout = (const float*)d_in[4];

  char* ws = (char*)d_ws;
  unsigned*       flags = (unsigned*)ws;                      // 4 KiB flag area
  unsigned short* Hbf   = (unsigned short*)(ws + 4096);       // 2 x 256 x 1024 bf16 = 1 MiB
  float*          Hy32  = (float*)(ws + 4096 + (size_t)2 * 256 * 1024 * 2);
  const size_t needed = 4096 + (size_t)2 * 256 * 1024 * 2 + (size_t)256 * 512 * 4;
  float* hyPtr = (ws_size >= needed) ? Hy32 : nullptr;

  hipMemsetAsync(flags, 0, 4096, stream);   // flags = 0 (ws is re-poisoned each launch)

  cornn_kernel<<<dim3(NWG), dim3(WG_THREADS), 0, stream>>>(x, W, bias, Hbf, hyPtr, flags);

  cornn_out_kernel<<<dim3(BATCH), dim3(64), 0, stream>>>(hyPtr, Hbf, Wout, bout,
                                                         (float*)d_out);
}

// Round 5
// 2227.436 us; speedup vs baseline: 1.1075x; 1.1075x over previous
//
#include <hip/hip_runtime.h>

#define T_STEPS 512
#define BATCH   256
#define N_INP   128
#define N_HID   512
#define N_OUT   10

#define DT_C     0.042f
#define GAMMA_C  2.7f
#define EPS_C    4.7f

#define NWG        64      // 8 m-groups (32 rows) x 8 n-tiles (64 cols)
#define GROUP_WGS  8       // WGs per row-group (share one flag set)
#define WG_THREADS 512     // 8 waves, 8-way K-split

typedef short          s16x8  __attribute__((ext_vector_type(8)));
typedef float          f32x16 __attribute__((ext_vector_type(16)));
typedef float          f32x4  __attribute__((ext_vector_type(4)));
typedef unsigned short u16x4  __attribute__((ext_vector_type(4)));
typedef unsigned long long u64;

__device__ inline unsigned short f2bf(float f) {
  union { float f; unsigned u; } v; v.f = f;
  unsigned r = v.u + 0x7fffu + ((v.u >> 16) & 1u);   // RNE
  return (unsigned short)(r >> 16);
}
__device__ inline float bf2f(unsigned short h) {
  union { unsigned u; float f; } v; v.u = ((unsigned)h) << 16;
  return v.f;
}

// ---- SLOW data plane: agent-scope write-through to IC. Proven R0/R4. ----
__device__ inline void pub8(unsigned short* p, u16x4 v) {
  union { u16x4 v; u64 q; } u; u.v = v;
  __hip_atomic_store((u64*)p, u.q, __ATOMIC_RELAXED, __HIP_MEMORY_SCOPE_AGENT);
}

// ---- FAST data plane (group co-resident on one XCD): sc0-only stores commit
// at the group's shared L2; ack (vmcnt(0)) lives in the SAME asm block since
// the backend doesn't model asm stores (R6 lesson). Control plane (flags)
// remains the proven IC protocol, so a wrong gate can only produce stale DATA
// (absmax fail), never a hang.
__device__ inline void pub_fast(unsigned short* pz, u16x4 vz,
                                unsigned short* py, u16x4 vy) {
  union { u16x4 v; u64 q; } uz, uy; uz.v = vz; uy.v = vy;
  asm volatile(
    "global_store_dwordx2 %0, %2, off sc0\n\t"
    "global_store_dwordx2 %1, %3, off sc0\n\t"
    "s_waitcnt vmcnt(0)"
    :: "v"(pz), "v"(py), "v"(uz.q), "v"(uy.q) : "memory");
}

// 8 coherent 16B loads + waitcnt fused in ONE asm block (R6 lesson). CP picks
// the read point: "sc0 sc1" = IC (cross-XCD), "sc0" = XCD L2.
#define STATE_LD8_CP(HB, HP, CP)                                             \
  asm volatile(                                                              \
    "global_load_dwordx4 %0, %8, off " CP "\n\t"                             \
    "global_load_dwordx4 %1, %8, off offset:32 " CP "\n\t"                   \
    "global_load_dwordx4 %2, %8, off offset:64 " CP "\n\t"                   \
    "global_load_dwordx4 %3, %8, off offset:96 " CP "\n\t"                   \
    "global_load_dwordx4 %4, %8, off offset:128 " CP "\n\t"                  \
    "global_load_dwordx4 %5, %8, off offset:160 " CP "\n\t"                  \
    "global_load_dwordx4 %6, %8, off offset:192 " CP "\n\t"                  \
    "global_load_dwordx4 %7, %8, off offset:224 " CP "\n\t"                  \
    "s_waitcnt vmcnt(0)"                                                     \
    : "=&v"(HB[0]), "=&v"(HB[1]), "=&v"(HB[2]), "=&v"(HB[3]),                \
      "=&v"(HB[4]), "=&v"(HB[5]), "=&v"(HB[6]), "=&v"(HB[7])                 \
    : "v"(HP)                                                                \
    : "memory")

// HW_REG_XCC_ID = hwreg id 20 (gfx940+), offset 0, size 4.
// SIMM16 = id | ((size-1)<<11). Raw-immediate builtin, no asm-name dependence.
#define XCC_ID_IMM ((20) | ((4 - 1) << 11))

// Persistent recurrent kernel (plain launch; 64 blocks of 8 waves => 1 WG/CU,
// trivially co-resident). Control protocol = EXACT R0 (agent/IC flags, both
// __syncthreads). x load at loop top (R4 post-mortem: prefetching it into the
// poll->flag window put its HBM latency on the critical chain, +180us).
// Hbf: double-buffered published state, bf16 [2][256][1024]; col c<512 = hz[c]
//      (W row 128+c), col 512+c = hy[c] (W row 640+c).
__global__ __launch_bounds__(WG_THREADS, 2) void cornn_kernel(
    const float* __restrict__ x, const float* __restrict__ W,
    const float* __restrict__ bias, unsigned short* __restrict__ Hbf,
    float* __restrict__ Hy32, unsigned* __restrict__ flags_ws) {
  const int tid   = threadIdx.x;
  const int lane  = tid & 63;
  const int ks    = tid >> 6;        // wave id 0..7 (8-way K-split)
  const int half  = lane >> 5;       // A/B frag k-half
  const int half8 = half << 3;
  const int lcol  = lane & 31;
  const int mi    = blockIdx.x & 7;  // row group
  const int ni    = blockIdx.x >> 3; // 64-col tile, 0..7
  const int rowA  = (mi << 5) + lcol;

  unsigned* gflags = flags_ws + mi * 64;   // 8 dwords used per group, 256B stride

  __shared__ float sC[8][2048];   // K-split partials (32 rows x 64 cols), 64 KB
  __shared__ float sB[64];

  // ---- stage W in registers: state 8 chunks/wave x 2 col-tiles (hi+lo),
  //      x 1 chunk/wave x 2 col-tiles (hi+lo) ----
  s16x8 whi0[8], wlo0[8], whi1[8], wlo1[8];
  s16x8 wxhi0, wxlo0, wxhi1, wxlo1;
  const int c0t = (ni << 6) + lcol;      // col tile 0
  #pragma unroll
  for (int i = 0; i < 8; ++i) {
    const int wr = 128 + (ks << 7) + i * 16 + half8;
    const float* wp0 = W + (size_t)wr * N_HID + c0t;
    s16x8 hi0, lo0, hi1, lo1;
    #pragma unroll
    for (int j = 0; j < 8; ++j) {
      float f0 = wp0[(size_t)j * N_HID];
      float f1 = wp0[(size_t)j * N_HID + 32];
      unsigned short h0 = f2bf(f0), h1 = f2bf(f1);
      hi0[j] = (short)h0;  lo0[j] = (short)f2bf(f0 - bf2f(h0));
      hi1[j] = (short)h1;  lo1[j] = (short)f2bf(f1 - bf2f(h1));
    }
    whi0[i] = hi0; wlo0[i] = lo0; whi1[i] = hi1; wlo1[i] = lo1;
  }
  {
    const int wr = (ks << 4) + half8;    // x chunk ks: k = ks*16
    const float* wp0 = W + (size_t)wr * N_HID + c0t;
    s16x8 hi0, lo0, hi1, lo1;
    #pragma unroll
    for (int j = 0; j < 8; ++j) {
      float f0 = wp0[(size_t)j * N_HID];
      float f1 = wp0[(size_t)j * N_HID + 32];
      unsigned short h0 = f2bf(f0), h1 = f2bf(f1);
      hi0[j] = (short)h0;  lo0[j] = (short)f2bf(f0 - bf2f(h0));
      hi1[j] = (short)h1;  lo1[j] = (short)f2bf(f1 - bf2f(h1));
    }
    wxhi0 = hi0; wxlo0 = lo0; wxhi1 = hi1; wxlo1 = lo1;
  }
  if (tid < 64) sB[tid] = bias[(ni << 6) + tid];

  // ---- per-thread fp32 state (4 cols each; 512 thr x 4 = 32 rows x 64 cols) ----
  const int e0   = tid << 2;
  const int rowL = e0 >> 6, c0 = e0 & 63;
  const int rowG = (mi << 5) + rowL;
  const int colG = (ni << 6) + c0;
  f32x4 hz = {0.f, 0.f, 0.f, 0.f};
  f32x4 hy = {0.f, 0.f, 0.f, 0.f};

  // state-read base pointers (per lane), one per buffer
  const unsigned short* hb2[2];
  hb2[0] = Hbf + (size_t)rowA * 1024 + (ks << 7) + half8;
  hb2[1] = hb2[0] + 256 * 1024;
  // publish pointers (per thread), one per buffer
  unsigned short* wz[2];
  unsigned short* wy[2];
  wz[0] = Hbf + (size_t)rowG * 1024 + colG;       wz[1] = wz[0] + 256 * 1024;
  wy[0] = wz[0] + 512;                            wy[1] = wz[1] + 512;

  // ---- one-time XCD topology detection, PLAUSIBILITY-GATED (data plane only).
  // Fast data plane engages only if (a) the hwreg demonstrably behaves like a
  // real XCC_ID (>=2 distinct values among the 64 WGs: genuine placement of
  // 64 WGs at 1/CU spans >=2 XCDs of 32 CUs) AND (b) this row-group is
  // co-resident on ONE XCD. Rendezvous termination needs all 64 WGs resident,
  // which the baseline flag-spin already requires (proven R0/R4). Slots are
  // monotone (written once) => all WGs read the same final values => verdict
  // is uniform. Flags/polls stay IC-scope regardless => no new hang mode; a
  // wrong verdict could only yield stale data => absmax fail, visible.
  const unsigned myxcc = __builtin_amdgcn_s_getreg(XCC_ID_IMM) & 0xfu;
  unsigned* xslots = flags_ws + 512;   // 64 dwords, bytes 2048..2303 (zeroed)
  if (tid == 0)
    __hip_atomic_store(&xslots[(mi << 3) | ni], myxcc + 1u,
                       __ATOMIC_RELAXED, __HIP_MEMORY_SCOPE_AGENT);
  bool fastp;
  {
    unsigned gmn, gmx, amn, amx;
    for (;;) {
      gmn = amn = 0xffffffffu; gmx = amx = 0u;
      for (int j = 0; j < 64; ++j) {
        unsigned v = __hip_atomic_load(&xslots[j], __ATOMIC_RELAXED, __HIP_MEMORY_SCOPE_AGENT);
        amn = v < amn ? v : amn;  amx = v > amx ? v : amx;
        if ((j >> 3) == mi) { gmn = v < gmn ? v : gmn;  gmx = v > gmx ? v : gmx; }
      }
      if (amn != 0u) break;     // all 64 WGs have reported
      __builtin_amdgcn_s_sleep(16);
    }
    fastp = (gmn == gmx) && (amn != amx);
  }

  __syncthreads();   // sB visible

  for (int t = 0; t < T_STEPS; ++t) {
    f32x16 acc0 = {};
    f32x16 acc1 = {};

    // ---- x-part (no state dep): loop-top load, latency sits in poll slack ----
    {
      const float* xp = x + (size_t)t * (BATCH * N_INP) + (size_t)rowA * N_INP
                        + (ks << 4) + half8;
      f32x4 a0 = *reinterpret_cast<const f32x4*>(xp);
      f32x4 a1 = *reinterpret_cast<const f32x4*>(xp + 4);
      s16x8 ahi, alo;
      #pragma unroll
      for (int j = 0; j < 4; ++j) {
        float f0 = a0[j], f1 = a1[j];
        unsigned short h0 = f2bf(f0), h1 = f2bf(f1);
        ahi[j]     = (short)h0;  ahi[j + 4] = (short)h1;
        alo[j]     = (short)f2bf(f0 - bf2f(h0));
        alo[j + 4] = (short)f2bf(f1 - bf2f(h1));
      }
      acc0 = __builtin_amdgcn_mfma_f32_32x32x16_bf16(ahi, wxhi0, acc0, 0, 0, 0);
      acc0 = __builtin_amdgcn_mfma_f32_32x32x16_bf16(ahi, wxlo0, acc0, 0, 0, 0);
      acc0 = __builtin_amdgcn_mfma_f32_32x32x16_bf16(alo, wxhi0, acc0, 0, 0, 0);
      acc1 = __builtin_amdgcn_mfma_f32_32x32x16_bf16(ahi, wxhi1, acc1, 0, 0, 0);
      acc1 = __builtin_amdgcn_mfma_f32_32x32x16_bf16(ahi, wxlo1, acc1, 0, 0, 0);
      acc1 = __builtin_amdgcn_mfma_f32_32x32x16_bf16(alo, wxhi1, acc1, 0, 0, 0);
    }

    if (t > 0) {
      // ---- per-wave poll of the 8 group flags (skip own; no join barrier).
      //      EXACT R0 protocol: agent/IC scope, proven. ----
      const unsigned ep = (unsigned)t;
      const int l = lane & 7;
      for (;;) {
        unsigned v = __hip_atomic_load(&gflags[l], __ATOMIC_RELAXED, __HIP_MEMORY_SCOPE_AGENT);
        if (__ballot((lane >= 8) | (l == ni) | (v >= ep)) == ~0ull) break;
        __builtin_amdgcn_s_sleep(2);
      }

      // ---- state part: 8 pipelined coherent 16B loads, ONE round-trip.
      // fast: producer committed at our shared L2 BEFORE its IC flag became
      // visible => sc0 read of that L2 is fresh. slow: IC read (proven). ----
      const unsigned short* hp = hb2[t & 1];
      f32x4 hbuf[8];
      if (fastp) { STATE_LD8_CP(hbuf, hp, "sc0"); }
      else       { STATE_LD8_CP(hbuf, hp, "sc0 sc1"); }

      #pragma unroll
      for (int i = 0; i < 8; ++i) {
        union { f32x4 f; s16x8 s; } u; u.f = hbuf[i];
        acc0 = __builtin_amdgcn_mfma_f32_32x32x16_bf16(u.s, whi0[i], acc0, 0, 0, 0);
        acc0 = __builtin_amdgcn_mfma_f32_32x32x16_bf16(u.s, wlo0[i], acc0, 0, 0, 0);
        acc1 = __builtin_amdgcn_mfma_f32_32x32x16_bf16(u.s, whi1[i], acc1, 0, 0, 0);
        acc1 = __builtin_amdgcn_mfma_f32_32x32x16_bf16(u.s, wlo1[i], acc1, 0, 0, 0);
      }
    }

    // ---- K-split partials (C/D layout: col=lane&31, row=(r&3)+8*(r>>2)+4*half) ----
    #pragma unroll
    for (int r = 0; r < 16; ++r) {
      const int rowL_r = (r & 3) + ((r >> 2) << 3) + (half << 2);
      sC[ks][rowL_r * 64 + lcol]      = acc0[r];
      sC[ks][rowL_r * 64 + 32 + lcol] = acc1[r];
    }
    __syncthreads();

    // ---- reduce (8-way) + tanh + state update + publish ----
    {
      f32x4 s = *reinterpret_cast<f32x4*>(&sC[0][e0]);
      #pragma unroll
      for (int w = 1; w < 8; ++w) s += *reinterpret_cast<f32x4*>(&sC[w][e0]);
      u16x4 pz, py;
      #pragma unroll
      for (int j = 0; j < 4; ++j) {
        float pre = tanhf(s[j] + sB[c0 + j]);
        float z = hz[j] + DT_C * (pre - GAMMA_C * hy[j] - EPS_C * hz[j]);
        float y = hy[j] + DT_C * z;
        hz[j] = z; hy[j] = y;
        pz[j] = f2bf(z); py[j] = f2bf(y);
      }
      const int wb = (t & 1) ^ 1;
      if (fastp) {
        pub_fast(wz[wb], pz, wy[wb], py);   // sc0 stores + in-block L2 ack
      } else {
        pub8(wz[wb], pz); pub8(wy[wb], py); // IC write-through (proven)
      }
    }
    __syncthreads();   // join + vmcnt drain: all publishes acked before flag
    if (tid == 0)
      __hip_atomic_store(&gflags[ni], (unsigned)t + 1u, __ATOMIC_RELAXED, __HIP_MEMORY_SCOPE_AGENT);
  }

  if (Hy32 != nullptr)
    *reinterpret_cast<f32x4*>(Hy32 + (size_t)rowG * 512 + colG) = hy;
}

// out[b][c] = sum_k hy[b][k] * Wout[k][c] + bout[c]
__global__ void cornn_out_kernel(const float* __restrict__ Hy32,
                                 const unsigned short* __restrict__ HbfFinal,
                                 const float* __restrict__ Wout,
                                 const float* __restrict__ bout,
                                 float* __restrict__ out) {
  const int b = blockIdx.x;
  const int lane = threadIdx.x;   // 64 threads
  float a[N_OUT];
  #pragma unroll
  for (int c = 0; c < N_OUT; ++c) a[c] = 0.f;
  #pragma unroll
  for (int j = 0; j < 8; ++j) {
    const int k = lane + (j << 6);
    const float h = Hy32 ? Hy32[(size_t)b * N_HID + k]
                         : bf2f(HbfFinal[(size_t)b * 1024 + 512 + k]);
    const float* wr = Wout + (size_t)k * N_OUT;
    #pragma unroll
    for (int c = 0; c < N_OUT; ++c) a[c] += h * wr[c];
  }
  #pragma unroll
  for (int c = 0; c < N_OUT; ++c) {
    float v = a[c];
    for (int off = 32; off > 0; off >>= 1) v += __shfl_down(v, off, 64);
    if (lane == 0) out[(size_t)b * N_OUT + c] = v + bout[c];
  }
}

extern "C" void kernel_launch(void* const* d_in, const int* in_sizes, int n_in,
                              void* d_out, int out_size, void* d_ws, size_t ws_size,
                              hipStream_t stream) {
  (void)in_sizes; (void)n_in; (void)out_size;
  const float* x    = (const float*)d_in[0];
  const float* W    = (const float*)d_in[1];
  const float* bias = (const float*)d_in[2];
  const float* Wout = (const float*)d_in[3];
  const float* bout = (const float*)d_in[4];

  char* ws = (char*)d_ws;
  unsigned*       flags = (unsigned*)ws;                      // 4 KiB flag+slot area
  unsigned short* Hbf   = (unsigned short*)(ws + 4096);       // 2 x 256 x 1024 bf16 = 1 MiB
  float*          Hy32  = (float*)(ws + 4096 + (size_t)2 * 256 * 1024 * 2);
  const size_t needed = 4096 + (size_t)2 * 256 * 1024 * 2 + (size_t)256 * 512 * 4;
  float* hyPtr = (ws_size >= needed) ? Hy32 : nullptr;

  hipMemsetAsync(flags, 0, 4096, stream);   // flags + xcd slots = 0

  cornn_kernel<<<dim3(NWG), dim3(WG_THREADS), 0, stream>>>(x, W, bias, Hbf, hyPtr, flags);

  cornn_out_kernel<<<dim3(BATCH), dim3(64), 0, stream>>>(hyPtr, Hbf, Wout, bout,
                                                         (float*)d_out);
}

// Round 7
// 2162.060 us; speedup vs baseline: 1.1410x; 1.0302x over previous
//
#include <hip/hip_runtime.h>

#define T_STEPS 512
#define BATCH   256
#define N_INP   128
#define N_HID   512
#define N_OUT   10

#define DT_C     0.042f
#define GAMMA_C  2.7f
#define EPS_C    4.7f

#define NWG        64      // 8 m-groups (32 rows) x 8 n-tiles (64 cols)
#define GROUP_WGS  8       // WGs per row-group (share one counter)
#define WG_THREADS 512     // 8 waves, 8-way K-split

typedef short          s16x8  __attribute__((ext_vector_type(8)));
typedef float          f32x16 __attribute__((ext_vector_type(16)));
typedef float          f32x4  __attribute__((ext_vector_type(4)));
typedef unsigned short u16x4  __attribute__((ext_vector_type(4)));
typedef unsigned long long u64;

__device__ inline unsigned short f2bf(float f) {
  union { float f; unsigned u; } v; v.f = f;
  unsigned r = v.u + 0x7fffu + ((v.u >> 16) & 1u);   // RNE
  return (unsigned short)(r >> 16);
}
__device__ inline float bf2f(unsigned short h) {
  union { unsigned u; float f; } v; v.u = ((unsigned)h) << 16;
  return v.f;
}

// ---- SLOW data plane: agent-scope write-through to IC. Proven R0/R4/R5. ----
__device__ inline void pub8(unsigned short* p, u16x4 v) {
  union { u16x4 v; u64 q; } u; u.v = v;
  __hip_atomic_store((u64*)p, u.q, __ATOMIC_RELAXED, __HIP_MEMORY_SCOPE_AGENT);
}

// ---- FAST data plane (group co-resident on one XCD; gate hardware-validated
// R5: engaged AND absmax-correct => the one-shot sc0 L2 reads saw fresh data).
// sc0 stores commit at the group's shared L2; ack (vmcnt(0)) lives in the SAME
// asm block since the backend doesn't model asm stores (R6 lesson).
// NOTE: sc0 is used ONLY for one-shot data accesses ordered after an IC-scope
// counter confirmation. sc0 SPINNING (flag polls) is banned: every kernel that
// polled an sc0 address died at container level (R1/R2/R3/R6); every kernel
// without it passed (R0/R4/R5).
__device__ inline void pub_fast(unsigned short* pz, u16x4 vz,
                                unsigned short* py, u16x4 vy) {
  union { u16x4 v; u64 q; } uz, uy; uz.v = vz; uy.v = vy;
  asm volatile(
    "global_store_dwordx2 %0, %2, off sc0\n\t"
    "global_store_dwordx2 %1, %3, off sc0\n\t"
    "s_waitcnt vmcnt(0)"
    :: "v"(pz), "v"(py), "v"(uz.q), "v"(uy.q) : "memory");
}

// 8 coherent 16B loads + waitcnt fused in ONE asm block (R6 lesson). CP picks
// the read point: "sc0 sc1" = IC (cross-XCD), "sc0" = XCD L2.
#define STATE_LD8_CP(HB, HP, CP)                                             \
  asm volatile(                                                              \
    "global_load_dwordx4 %0, %8, off " CP "\n\t"                             \
    "global_load_dwordx4 %1, %8, off offset:32 " CP "\n\t"                   \
    "global_load_dwordx4 %2, %8, off offset:64 " CP "\n\t"                   \
    "global_load_dwordx4 %3, %8, off offset:96 " CP "\n\t"                   \
    "global_load_dwordx4 %4, %8, off offset:128 " CP "\n\t"                  \
    "global_load_dwordx4 %5, %8, off offset:160 " CP "\n\t"                  \
    "global_load_dwordx4 %6, %8, off offset:192 " CP "\n\t"                  \
    "global_load_dwordx4 %7, %8, off offset:224 " CP "\n\t"                  \
    "s_waitcnt vmcnt(0)"                                                     \
    : "=&v"(HB[0]), "=&v"(HB[1]), "=&v"(HB[2]), "=&v"(HB[3]),                \
      "=&v"(HB[4]), "=&v"(HB[5]), "=&v"(HB[6]), "=&v"(HB[7])                 \
    : "v"(HP)                                                                \
    : "memory")

// HW_REG_XCC_ID = hwreg id 20 (gfx940+), offset 0, size 4.
// SIMM16 = id | ((size-1)<<11). Raw-immediate builtin, no asm-name dependence.
#define XCC_ID_IMM ((20) | ((4 - 1) << 11))

// Persistent recurrent kernel (plain launch; 64 blocks of 8 waves => 1 WG/CU,
// trivially co-resident).
// Hbf: double-buffered published state, bf16 [2][256][1024]; col c<512 = hz[c]
//      (W row 128+c), col 512+c = hy[c] (W row 640+c).
// Control plane: ONE agent-scope counter per row-group. Producers atomicAdd 1
// per step (fire-and-forget, executes at the IC); consumers wait for
// gcnt >= 8*t. Only wave 0 polls, with a wave-uniform address (64 lanes load
// the SAME dword -> one request per iteration), then __syncthreads releases
// the other waves. This cuts IC poll traffic 64x vs the R0/R5 per-lane
// 8-flag poll (4096 lane-pollers -> 64 wave-pollers).
__global__ __launch_bounds__(WG_THREADS, 2) void cornn_kernel(
    const float* __restrict__ x, const float* __restrict__ W,
    const float* __restrict__ bias, unsigned short* __restrict__ Hbf,
    float* __restrict__ Hy32, unsigned* __restrict__ flags_ws) {
  const int tid   = threadIdx.x;
  const int lane  = tid & 63;
  const int ks    = tid >> 6;        // wave id 0..7 (8-way K-split)
  const int half  = lane >> 5;       // A/B frag k-half
  const int half8 = half << 3;
  const int lcol  = lane & 31;
  const int mi    = blockIdx.x & 7;  // row group
  const int ni    = blockIdx.x >> 3; // 64-col tile, 0..7
  const int rowA  = (mi << 5) + lcol;

  unsigned* gcnt = flags_ws + mi * 64;   // one dword per group, 256B stride

  __shared__ float sC[8][2048];   // K-split partials (32 rows x 64 cols), 64 KB
  __shared__ float sB[64];

  // ---- stage W in registers: state 8 chunks/wave x 2 col-tiles (hi+lo),
  //      x 1 chunk/wave x 2 col-tiles (hi+lo) ----
  s16x8 whi0[8], wlo0[8], whi1[8], wlo1[8];
  s16x8 wxhi0, wxlo0, wxhi1, wxlo1;
  const int c0t = (ni << 6) + lcol;      // col tile 0
  #pragma unroll
  for (int i = 0; i < 8; ++i) {
    const int wr = 128 + (ks << 7) + i * 16 + half8;
    const float* wp0 = W + (size_t)wr * N_HID + c0t;
    s16x8 hi0, lo0, hi1, lo1;
    #pragma unroll
    for (int j = 0; j < 8; ++j) {
      float f0 = wp0[(size_t)j * N_HID];
      float f1 = wp0[(size_t)j * N_HID + 32];
      unsigned short h0 = f2bf(f0), h1 = f2bf(f1);
      hi0[j] = (short)h0;  lo0[j] = (short)f2bf(f0 - bf2f(h0));
      hi1[j] = (short)h1;  lo1[j] = (short)f2bf(f1 - bf2f(h1));
    }
    whi0[i] = hi0; wlo0[i] = lo0; whi1[i] = hi1; wlo1[i] = lo1;
  }
  {
    const int wr = (ks << 4) + half8;    // x chunk ks: k = ks*16
    const float* wp0 = W + (size_t)wr * N_HID + c0t;
    s16x8 hi0, lo0, hi1, lo1;
    #pragma unroll
    for (int j = 0; j < 8; ++j) {
      float f0 = wp0[(size_t)j * N_HID];
      float f1 = wp0[(size_t)j * N_HID + 32];
      unsigned short h0 = f2bf(f0), h1 = f2bf(f1);
      hi0[j] = (short)h0;  lo0[j] = (short)f2bf(f0 - bf2f(h0));
      hi1[j] = (short)h1;  lo1[j] = (short)f2bf(f1 - bf2f(h1));
    }
    wxhi0 = hi0; wxlo0 = lo0; wxhi1 = hi1; wxlo1 = lo1;
  }
  if (tid < 64) sB[tid] = bias[(ni << 6) + tid];

  // ---- per-thread fp32 state (4 cols each; 512 thr x 4 = 32 rows x 64 cols) ----
  const int e0   = tid << 2;
  const int rowL = e0 >> 6, c0 = e0 & 63;
  const int rowG = (mi << 5) + rowL;
  const int colG = (ni << 6) + c0;
  f32x4 hz = {0.f, 0.f, 0.f, 0.f};
  f32x4 hy = {0.f, 0.f, 0.f, 0.f};

  // state-read base pointers (per lane), one per buffer
  const unsigned short* hb2[2];
  hb2[0] = Hbf + (size_t)rowA * 1024 + (ks << 7) + half8;
  hb2[1] = hb2[0] + 256 * 1024;
  // publish pointers (per thread), one per buffer
  unsigned short* wz[2];
  unsigned short* wy[2];
  wz[0] = Hbf + (size_t)rowG * 1024 + colG;       wz[1] = wz[0] + 256 * 1024;
  wy[0] = wz[0] + 512;                            wy[1] = wz[1] + 512;

  // ---- one-time XCD topology detection, PLAUSIBILITY-GATED (R5: validated on
  // hardware — engaged AND absmax-correct). Gates the DATA plane only. Fast
  // engages only if (a) the hwreg shows >=2 distinct values among the 64 WGs
  // (genuine placement of 64 WGs at 1/CU spans >=2 XCDs of 32 CUs) AND (b)
  // this row-group is co-resident on ONE XCD. Rendezvous termination needs all
  // 64 WGs resident, already required by the baseline spin (proven R0/R4/R5).
  // Slots are monotone => verdict uniform across each group.
  const unsigned myxcc = __builtin_amdgcn_s_getreg(XCC_ID_IMM) & 0xfu;
  unsigned* xslots = flags_ws + 512;   // 64 dwords, bytes 2048..2303 (zeroed)
  if (tid == 0)
    __hip_atomic_store(&xslots[(mi << 3) | ni], myxcc + 1u,
                       __ATOMIC_RELAXED, __HIP_MEMORY_SCOPE_AGENT);
  bool fastp;
  {
    unsigned gmn, gmx, amn, amx;
    for (;;) {
      gmn = amn = 0xffffffffu; gmx = amx = 0u;
      for (int j = 0; j < 64; ++j) {
        unsigned v = __hip_atomic_load(&xslots[j], __ATOMIC_RELAXED, __HIP_MEMORY_SCOPE_AGENT);
        amn = v < amn ? v : amn;  amx = v > amx ? v : amx;
        if ((j >> 3) == mi) { gmn = v < gmn ? v : gmn;  gmx = v > gmx ? v : gmx; }
      }
      if (amn != 0u) break;     // all 64 WGs have reported
      __builtin_amdgcn_s_sleep(16);
    }
    fastp = (gmn == gmx) && (amn != amx);
  }

  __syncthreads();   // sB visible

  // ---- 2-deep x register pipeline (R4 post-mortem applied): x(t+1) issued at
  // the VERY TOP of iteration t, so its ~900cy latency runs concurrent with
  // the counter wait instead of sitting serially at consume time. The first
  // mandatory drain it can hit is the poll's/STATE_LD8's vmcnt — by which
  // point the wait has covered it. sched_barrier is compile-time only. ----
  const float* xbase = x + (size_t)rowA * N_INP + (ks << 4) + half8;
  f32x4 xr0 = *reinterpret_cast<const f32x4*>(xbase);
  f32x4 xr1 = *reinterpret_cast<const f32x4*>(xbase + 4);

  for (int t = 0; t < T_STEPS; ++t) {
    const float* xpn =
        xbase + (size_t)((t + 1 < T_STEPS) ? t + 1 : t) * (BATCH * N_INP);
    f32x4 xn0 = *reinterpret_cast<const f32x4*>(xpn);
    f32x4 xn1 = *reinterpret_cast<const f32x4*>(xpn + 4);
    __builtin_amdgcn_sched_barrier(0);

    f32x16 acc0 = {};
    f32x16 acc1 = {};

    // ---- x-part (no state dep): consume x(t) from registers ----
    {
      s16x8 ahi, alo;
      #pragma unroll
      for (int j = 0; j < 4; ++j) {
        float f0 = xr0[j], f1 = xr1[j];
        unsigned short h0 = f2bf(f0), h1 = f2bf(f1);
        ahi[j]     = (short)h0;  ahi[j + 4] = (short)h1;
        alo[j]     = (short)f2bf(f0 - bf2f(h0));
        alo[j + 4] = (short)f2bf(f1 - bf2f(h1));
      }
      acc0 = __builtin_amdgcn_mfma_f32_32x32x16_bf16(ahi, wxhi0, acc0, 0, 0, 0);
      acc0 = __builtin_amdgcn_mfma_f32_32x32x16_bf16(ahi, wxlo0, acc0, 0, 0, 0);
      acc0 = __builtin_amdgcn_mfma_f32_32x32x16_bf16(alo, wxhi0, acc0, 0, 0, 0);
      acc1 = __builtin_amdgcn_mfma_f32_32x32x16_bf16(ahi, wxhi1, acc1, 0, 0, 0);
      acc1 = __builtin_amdgcn_mfma_f32_32x32x16_bf16(ahi, wxlo1, acc1, 0, 0, 0);
      acc1 = __builtin_amdgcn_mfma_f32_32x32x16_bf16(alo, wxhi1, acc1, 0, 0, 0);
    }

    if (t > 0) {
      // ---- counter wait: wave 0 only, wave-uniform address (one request per
      // iteration), agent-scope (proven machinery). Others wait at the join
      // barrier. counter >= 8*t <=> all 8 group WGs finished step t-1. ----
      if (ks == 0) {
        const unsigned tgt = 8u * (unsigned)t;
        for (;;) {
          unsigned v = __hip_atomic_load(gcnt, __ATOMIC_RELAXED, __HIP_MEMORY_SCOPE_AGENT);
          if (v >= tgt) break;
          __builtin_amdgcn_s_sleep(1);
        }
      }
      __syncthreads();   // release waves 1..7 once wave 0 saw the counter

      // ---- state part: 8 pipelined coherent 16B loads, ONE round-trip.
      // fast: producer committed at our shared L2 BEFORE its IC counter add
      // became visible => one-shot sc0 read is fresh (R5-proven). ----
      const unsigned short* hp = hb2[t & 1];
      f32x4 hbuf[8];
      if (fastp) { STATE_LD8_CP(hbuf, hp, "sc0"); }
      else       { STATE_LD8_CP(hbuf, hp, "sc0 sc1"); }

      #pragma unroll
      for (int i = 0; i < 8; ++i) {
        union { f32x4 f; s16x8 s; } u; u.f = hbuf[i];
        acc0 = __builtin_amdgcn_mfma_f32_32x32x16_bf16(u.s, whi0[i], acc0, 0, 0, 0);
        acc0 = __builtin_amdgcn_mfma_f32_32x32x16_bf16(u.s, wlo0[i], acc0, 0, 0, 0);
        acc1 = __builtin_amdgcn_mfma_f32_32x32x16_bf16(u.s, whi1[i], acc1, 0, 0, 0);
        acc1 = __builtin_amdgcn_mfma_f32_32x32x16_bf16(u.s, wlo1[i], acc1, 0, 0, 0);
      }
    }

    // ---- K-split partials (C/D layout: col=lane&31, row=(r&3)+8*(r>>2)+4*half) ----
    #pragma unroll
    for (int r = 0; r < 16; ++r) {
      const int rowL_r = (r & 3) + ((r >> 2) << 3) + (half << 2);
      sC[ks][rowL_r * 64 + lcol]      = acc0[r];
      sC[ks][rowL_r * 64 + 32 + lcol] = acc1[r];
    }
    __syncthreads();

    // ---- reduce (8-way) + tanh + state update + publish ----
    {
      f32x4 s = *reinterpret_cast<f32x4*>(&sC[0][e0]);
      #pragma unroll
      for (int w = 1; w < 8; ++w) s += *reinterpret_cast<f32x4*>(&sC[w][e0]);
      u16x4 pz, py;
      #pragma unroll
      for (int j = 0; j < 4; ++j) {
        float pre = tanhf(s[j] + sB[c0 + j]);
        float z = hz[j] + DT_C * (pre - GAMMA_C * hy[j] - EPS_C * hz[j]);
        float y = hy[j] + DT_C * z;
        hz[j] = z; hy[j] = y;
        pz[j] = f2bf(z); py[j] = f2bf(y);
      }
      const int wb = (t & 1) ^ 1;
      if (fastp) {
        pub_fast(wz[wb], pz, wy[wb], py);   // sc0 stores + in-block L2 ack
      } else {
        pub8(wz[wb], pz); pub8(wy[wb], py); // IC write-through (proven)
      }
    }
    __syncthreads();   // join + drain: all waves' publishes acked before the add
    if (tid == 0)
      __hip_atomic_fetch_add(gcnt, 1u, __ATOMIC_RELAXED, __HIP_MEMORY_SCOPE_AGENT);
    xr0 = xn0; xr1 = xn1;
  }

  if (Hy32 != nullptr)
    *reinterpret_cast<f32x4*>(Hy32 + (size_t)rowG * 512 + colG) = hy;
}

// out[b][c] = sum_k hy[b][k] * Wout[k][c] + bout[c]
__global__ void cornn_out_kernel(const float* __restrict__ Hy32,
                                 const unsigned short* __restrict__ HbfFinal,
                                 const float* __restrict__ Wout,
                                 const float* __restrict__ bout,
                                 float* __restrict__ out) {
  const int b = blockIdx.x;
  const int lane = threadIdx.x;   // 64 threads
  float a[N_OUT];
  #pragma unroll
  for (int c = 0; c < N_OUT; ++c) a[c] = 0.f;
  #pragma unroll
  for (int j = 0; j < 8; ++j) {
    const int k = lane + (j << 6);
    const float h = Hy32 ? Hy32[(size_t)b * N_HID + k]
                         : bf2f(HbfFinal[(size_t)b * 1024 + 512 + k]);
    const float* wr = Wout + (size_t)k * N_OUT;
    #pragma unroll
    for (int c = 0; c < N_OUT; ++c) a[c] += h * wr[c];
  }
  #pragma unroll
  for (int c = 0; c < N_OUT; ++c) {
    float v = a[c];
    for (int off = 32; off > 0; off >>= 1) v += __shfl_down(v, off, 64);
    if (lane == 0) out[(size_t)b * N_OUT + c] = v + bout[c];
  }
}

extern "C" void kernel_launch(void* const* d_in, const int* in_sizes, int n_in,
                              void* d_out, int out_size, void* d_ws, size_t ws_size,
                              hipStream_t stream) {
  (void)in_sizes; (void)n_in; (void)out_size;
  const float* x    = (const float*)d_in[0];
  const float* W    = (const float*)d_in[1];
  const float* bias = (const float*)d_in[2];
  const float* Wout = (const float*)d_in[3];
  const float* bout = (const float*)d_in[4];

  char* ws = (char*)d_ws;
  unsigned*       flags = (unsigned*)ws;                      // 4 KiB counter+slot area
  unsigned short* Hbf   = (unsigned short*)(ws + 4096);       // 2 x 256 x 1024 bf16 = 1 MiB
  float*          Hy32  = (float*)(ws + 4096 + (size_t)2 * 256 * 1024 * 2);
  const size_t needed = 4096 + (size_t)2 * 256 * 1024 * 2 + (size_t)256 * 512 * 4;
  float* hyPtr = (ws_size >= needed) ? Hy32 : nullptr;

  hipMemsetAsync(flags, 0, 4096, stream);   // counters + xcd slots = 0

  cornn_kernel<<<dim3(NWG), dim3(WG_THREADS), 0, stream>>>(x, W, bias, Hbf, hyPtr, flags);

  cornn_out_kernel<<<dim3(BATCH), dim3(64), 0, stream>>>(hyPtr, Hbf, Wout, bout,
                                                         (float*)d_out);
}